// Round 6
// baseline (105.455 us; speedup 1.0000x reference)
//
#include <hip/hip_runtime.h>

// LIF SNN, 50 timesteps x 8192 neurons.
// 1) prep:          x f32 -> bf16 (padded to 64 t, vectorized), zero flag
// 2) ff_gemm_mfma:  P[ks][t][j] = sum_{k in chunk} x[t][k]*w_in[j][k] via bf16
//                   MFMA. Page-friendly staging: each wave fetches a FULL 2 KB
//                   row-chunk of w_in sequentially (depth-4 reg pipeline),
//                   cvt->bf16, 64 KB swizzled LDS tile; compute = 16 K-steps
//                   of ds_read_b128 + MFMA. 2 blocks/CU overlap stage/compute.
// 3) reduce_ff:     FF = sum of 16 bf16 partials (f32 accumulate)
// 4) spec_scan:     per-neuron scan assuming no spikes (threshold margin ~15
//                   units); 50 FF values prefetched; flags if any spike
// 5) lif_fallback:  exact sequential event-driven scan, runs only if flagged

#define NEUR 8192
#define TSTEPS 50
#define TPAD 64

typedef __attribute__((ext_vector_type(8))) short bs8;           // 8 bf16
typedef __attribute__((ext_vector_type(4))) float fx4;           // MFMA C/D
typedef __attribute__((ext_vector_type(8))) unsigned short us8;  // 8 bf16 bits

static __device__ __forceinline__ unsigned short f2b(float f) {
    // f32 -> bf16 round-to-nearest-even
    unsigned u = __float_as_uint(f);
    return (unsigned short)((u + 0x7FFFu + ((u >> 16) & 1u)) >> 16);
}
static __device__ __forceinline__ float b2f(unsigned short b) {
    return __uint_as_float(((unsigned)b) << 16);
}

// ---------------- K0: convert x (vectorized), zero flag ----------------
__global__ __launch_bounds__(256)
void prep(const float* __restrict__ x, unsigned short* __restrict__ xb,
          int* __restrict__ flag)
{
    const int e8 = blockIdx.x * 256 + threadIdx.x;   // < TPAD*NEUR/8 = 65536
    const int e  = e8 * 8;
    const int t  = e >> 13;
    us8 o;
    if (t < TSTEPS) {
        const float4 lo = *(const float4*)&x[e];
        const float4 hi = *(const float4*)&x[e + 4];
        o = (us8){f2b(lo.x), f2b(lo.y), f2b(lo.z), f2b(lo.w),
                  f2b(hi.x), f2b(hi.y), f2b(hi.z), f2b(hi.w)};
    } else {
        o = (us8){0, 0, 0, 0, 0, 0, 0, 0};
    }
    *(us8*)&xb[e] = o;
    if (e8 == 0) *flag = 0;
}

// ---------------- K1: feed-forward GEMM, page-sequential staged ----------------
// grid = 128 j-blocks (64 j each) x 16 k-splits = 2048; block = 4 waves.
// Stage: 16 rounds; round r: wave wv fetches row r*4+wv's full 2 KB chunk.
// Compute: wave wv owns j-subtile wv*16..+15, all 64 t, 16 K-steps.
#define BJ 64
#define KC 512
#define KSPLIT 16
#define NKSTEP (KC / 32)          // 16

__global__ __launch_bounds__(256, 2)   // 2 waves/EU -> 2 blocks/CU (LDS-limited)
void ff_gemm_mfma(const float* __restrict__ w,            // [8192][8192]
                  const unsigned short* __restrict__ xb,  // [64][8192] bf16 bits
                  unsigned short* __restrict__ P)         // [KSPLIT][50][8192] bf16
{
    __shared__ __align__(16) unsigned char smem[BJ * KC * 2];   // 64 KB bf16 tile

    const int tid  = threadIdx.x;
    const int wv   = tid >> 6;
    const int lane = tid & 63;
    const int jb   = blockIdx.x & 127;    // 128 j-blocks
    const int ks   = blockIdx.x >> 7;     // 16 k-splits
    const int j0   = jb * BJ;
    const int k0   = ks * KC;

    // ---- stage phase: each wave reads one full row-chunk (2 KB) per round ----
    const float* const wst = w + (size_t)(j0 + wv) * NEUR + k0 + lane * 8;

    float4 S0a, S0b, S1a, S1b, S2a, S2b, S3a, S3b;
#define SLD(q, r)                                                        \
    do { const float* p_ = wst + (size_t)(r) * 4 * NEUR;                 \
         S##q##a = *(const float4*)(p_);                                 \
         S##q##b = *(const float4*)(p_ + 4); } while (0)
#define SST(q, r)                                                        \
    do { const int row_ = (r) * 4 + wv;                                  \
         const us8 o_ = {f2b(S##q##a.x), f2b(S##q##a.y), f2b(S##q##a.z), \
                         f2b(S##q##a.w), f2b(S##q##b.x), f2b(S##q##b.y), \
                         f2b(S##q##b.z), f2b(S##q##b.w)};                \
         *(us8*)(smem + row_ * 1024 +                                    \
                 ((lane * 16) ^ ((row_ & 7) << 4))) = o_; } while (0)

    SLD(0, 0);  SLD(1, 1);  SLD(2, 2);  SLD(3, 3);
    SST(0, 0);  SLD(0, 4);  SST(1, 1);  SLD(1, 5);
    SST(2, 2);  SLD(2, 6);  SST(3, 3);  SLD(3, 7);
    SST(0, 4);  SLD(0, 8);  SST(1, 5);  SLD(1, 9);
    SST(2, 6);  SLD(2, 10); SST(3, 7);  SLD(3, 11);
    SST(0, 8);  SLD(0, 12); SST(1, 9);  SLD(1, 13);
    SST(2, 10); SLD(2, 14); SST(3, 11); SLD(3, 15);
    SST(0, 12); SST(1, 13); SST(2, 14); SST(3, 15);
#undef SLD
#undef SST

    __syncthreads();

    // ---- compute phase ----
    const int lrow = lane & 15;           // fragment free-dim index
    const int lgrp = lane >> 4;           // k-group (0..3), 8 k each
    const int swz  = (lrow & 7) << 4;
    const unsigned char* const brow = smem + (wv * 16 + lrow) * 1024;

    const unsigned short* const xq0 = xb + (size_t)lrow * NEUR + k0 + lgrp * 8;
    const unsigned short* const xq1 = xq0 + (size_t)16 * NEUR;
    const unsigned short* const xq2 = xq0 + (size_t)32 * NEUR;
    const unsigned short* const xq3 = xq0 + (size_t)48 * NEUR;

    fx4 acc[4];
#pragma unroll
    for (int tb = 0; tb < 4; ++tb) acc[tb] = (fx4){0.f, 0.f, 0.f, 0.f};

    bs8 Ae[4], Ao[4], Be, Bo;
#define ALOAD(AS, KK)                                   \
    do { AS[0] = *(const bs8*)(xq0 + (KK) * 32);        \
         AS[1] = *(const bs8*)(xq1 + (KK) * 32);        \
         AS[2] = *(const bs8*)(xq2 + (KK) * 32);        \
         AS[3] = *(const bs8*)(xq3 + (KK) * 32); } while (0)
#define BLOAD(BS, KK)                                                        \
    do { BS = *(const bs8*)(brow + ((((KK) * 4 + lgrp) << 4) ^ swz)); } while (0)
#define MM(AS, BS)                                                                       \
    do { acc[0] = __builtin_amdgcn_mfma_f32_16x16x32_bf16(AS[0], BS, acc[0], 0, 0, 0);   \
         acc[1] = __builtin_amdgcn_mfma_f32_16x16x32_bf16(AS[1], BS, acc[1], 0, 0, 0);   \
         acc[2] = __builtin_amdgcn_mfma_f32_16x16x32_bf16(AS[2], BS, acc[2], 0, 0, 0);   \
         acc[3] = __builtin_amdgcn_mfma_f32_16x16x32_bf16(AS[3], BS, acc[3], 0, 0, 0); } while (0)
#define STEPL(ANX, BNX, KN, AC, BC)                                  \
    do { ALOAD(ANX, KN); BLOAD(BNX, KN); MM(AC, BC); } while (0)

    ALOAD(Ae, 0); BLOAD(Be, 0);
    STEPL(Ao, Bo, 1,  Ae, Be);
    STEPL(Ae, Be, 2,  Ao, Bo);
    STEPL(Ao, Bo, 3,  Ae, Be);
    STEPL(Ae, Be, 4,  Ao, Bo);
    STEPL(Ao, Bo, 5,  Ae, Be);
    STEPL(Ae, Be, 6,  Ao, Bo);
    STEPL(Ao, Bo, 7,  Ae, Be);
    STEPL(Ae, Be, 8,  Ao, Bo);
    STEPL(Ao, Bo, 9,  Ae, Be);
    STEPL(Ae, Be, 10, Ao, Bo);
    STEPL(Ao, Bo, 11, Ae, Be);
    STEPL(Ae, Be, 12, Ao, Bo);
    STEPL(Ao, Bo, 13, Ae, Be);
    STEPL(Ae, Be, 14, Ao, Bo);
    STEPL(Ao, Bo, 15, Ae, Be);
    MM(Ao, Bo);
#undef ALOAD
#undef BLOAD
#undef MM
#undef STEPL

    // epilogue: C/D layout col = lane&15 (-> j), row = (lane>>4)*4 + reg (-> t)
#pragma unroll
    for (int tb = 0; tb < 4; ++tb)
#pragma unroll
        for (int i = 0; i < 4; ++i) {
            const int t = tb * 16 + lgrp * 4 + i;
            if (t < TSTEPS)
                P[((size_t)ks * TSTEPS + t) * NEUR + j0 + wv * 16 + lrow] =
                    f2b(acc[tb][i]);
        }
}

// ---------------- K2: reduce bf16 partials -> FF f32 ----------------
__global__ __launch_bounds__(256)
void reduce_ff(const unsigned short* __restrict__ P, float* __restrict__ FF)
{
    const int i = (blockIdx.x * 256 + threadIdx.x) * 8;   // 200 blocks
    float s[8];
#pragma unroll
    for (int n = 0; n < 8; ++n) s[n] = 0.f;
#pragma unroll
    for (int ks = 0; ks < KSPLIT; ++ks) {
        const us8 p = *(const us8*)&P[(size_t)ks * TSTEPS * NEUR + i];
#pragma unroll
        for (int n = 0; n < 8; ++n) s[n] += b2f(p[n]);
    }
    *(float4*)&FF[i]     = make_float4(s[0], s[1], s[2], s[3]);
    *(float4*)&FF[i + 4] = make_float4(s[4], s[5], s[6], s[7]);
}

// ---------------- K3: speculative parallel scan (assumes z == 0) ----------------
__global__ __launch_bounds__(256)
void spec_scan(const float* __restrict__ FF, float* __restrict__ out,
               int* __restrict__ flag)
{
    const int j = blockIdx.x * 256 + threadIdx.x;   // one neuron per thread
    float ff[TSTEPS];                               // full prefetch, static idx
#pragma unroll
    for (int t = 0; t < TSTEPS; ++t) ff[t] = FF[(size_t)t * NEUR + j];

    float v = -70.f, cur = 0.f;
    bool any = false;
#pragma unroll
    for (int t = 0; t < TSTEPS; ++t) {
        const float vd = v + 5.0e-5f * ((-70.f - v) + cur);
        const float id = cur - 1.0e-4f * cur;
        const bool sp = vd > -55.f;
        any |= sp;
        v = sp ? -70.f : vd;
        cur = id + ff[t];                           // no recurrence (speculation)
        out[(size_t)t * NEUR + j] = sp ? 1.f : 0.f;
    }
    if (any) atomicAdd(flag, 1);
}

// ---------------- K4: exact event-driven fallback (only if spikes occurred) ----------------
__global__ __launch_bounds__(1024)
void lif_fallback(const float* __restrict__ FF, const float* __restrict__ wrec,
                  float* __restrict__ out, const int* __restrict__ flag)
{
    if (*flag == 0) return;   // speculation was self-consistent -> out is exact

    const int tid = threadIdx.x;
    __shared__ unsigned short list[2][NEUR];
    __shared__ int cnt[2];

    float v[8], cur[8];
#pragma unroll
    for (int n = 0; n < 8; ++n) { v[n] = -70.0f; cur[n] = 0.0f; }
    if (tid == 0) { cnt[0] = 0; cnt[1] = 0; }

    for (int t = 0; t < TSTEPS; ++t) {
        const int rb = t & 1, wb = rb ^ 1;
        __syncthreads();
        if (tid == 0) cnt[wb] = 0;
        __syncthreads();

        float rec[8];
#pragma unroll
        for (int n = 0; n < 8; ++n) rec[n] = 0.0f;
        const int c = cnt[rb];
        for (int s = 0; s < c; ++s) {
            const int k = list[rb][s];
#pragma unroll
            for (int n = 0; n < 8; ++n)
                rec[n] += wrec[(size_t)(tid + n * 1024) * NEUR + k];
        }

#pragma unroll
        for (int n = 0; n < 8; ++n) {
            const float ff = FF[(size_t)t * NEUR + tid + n * 1024];
            const float vd = v[n] + 5.0e-5f * ((-70.0f - v[n]) + cur[n]);
            const float id = cur[n] - 1.0e-4f * cur[n];
            const bool  sp = vd > -55.0f;
            v[n]   = sp ? -70.0f : vd;
            cur[n] = id + ff + rec[n];
            out[(size_t)t * NEUR + tid + n * 1024] = sp ? 1.0f : 0.0f;
            if (sp) {
                const int pos = atomicAdd(&cnt[wb], 1);
                list[wb][pos] = (unsigned short)(tid + n * 1024);
            }
        }
    }
}

extern "C" void kernel_launch(void* const* d_in, const int* in_sizes, int n_in,
                              void* d_out, int out_size, void* d_ws, size_t ws_size,
                              hipStream_t stream) {
    const float* x     = (const float*)d_in[0];   // [50][8192]
    const float* w_in  = (const float*)d_in[1];   // [8192][8192]
    const float* w_rec = (const float*)d_in[2];   // [8192][8192]
    float* out = (float*)d_out;

    // ws layout (16B-aligned):
    //   FF  f32  [50][8192]          1,638,400 B  @ 0
    //   xb  bf16 [64][8192]          1,048,576 B  @ 1,638,400
    //   P   bf16 [16][50][8192]     13,107,200 B  @ 2,686,976
    //   flag int                            4 B  @ 15,794,176
    float* FF          = (float*)d_ws;
    unsigned short* xb = (unsigned short*)((char*)d_ws + 1638400);
    unsigned short* P  = (unsigned short*)((char*)d_ws + 2686976);
    int* flag          = (int*)((char*)d_ws + 15794176);

    prep        <<<dim3(TPAD * NEUR / 8 / 256),    dim3(256),  0, stream>>>(x, xb, flag);
    ff_gemm_mfma<<<dim3((NEUR / BJ) * KSPLIT),     dim3(256),  0, stream>>>(w_in, xb, P);
    reduce_ff   <<<dim3(TSTEPS * NEUR / 8 / 256),  dim3(256),  0, stream>>>(P, FF);
    spec_scan   <<<dim3(NEUR / 256),               dim3(256),  0, stream>>>(FF, out, flag);
    lif_fallback<<<dim3(1),                        dim3(1024), 0, stream>>>(FF, w_rec, out, flag);
}